// Round 18
// baseline (153.860 us; speedup 1.0000x reference)
//
#include <hip/hip_runtime.h>
#include <hip/hip_bf16.h>

#define B_ 4
#define S_ 1024
#define D_ 1024
#define H_ 16
#define M_ 4096  // B_*S_

typedef unsigned short u16;
typedef __attribute__((ext_vector_type(4))) float f32x4;
typedef __attribute__((ext_vector_type(16))) float f32x16;
typedef __attribute__((ext_vector_type(8))) short short8;
typedef __attribute__((ext_vector_type(4))) u16 u16x4;

__device__ inline u16 f2bf(float f) {
  return __builtin_bit_cast(u16, __float2bfloat16(f));
}

__device__ inline short8 ldfrag(const u16* p) {
  return *reinterpret_cast<const short8*>(p);
}

__device__ inline float fast_exp2(float x) {
  return __builtin_amdgcn_exp2f(x);   // native v_exp_f32 (2^x), no libm path
}

__device__ inline void gload_lds16(const void* g, void* l) {
  __builtin_amdgcn_global_load_lds((const __attribute__((address_space(1))) void*)g,
                                   (__attribute__((address_space(3))) void*)l,
                                   16, 0, 0);
}

// sigma: swap bits 2 and 3 of the sequence index (4-group granular involution)
__device__ inline int sigma_s(int s) {
  return (s & ~12) | ((s & 4) << 1) | ((s & 8) >> 1);
}

struct GArgs {
  const void* A[6];
  const void* W[6];
  const float* bias[6];
  void* C[6];
  float oscale[6];
  int vtrans[6];
};

// ---------------- fp32 -> bf16 bulk convert ----------------
struct CvtArgs {
  const float* src[11];
  u16* dst[11];
  int n4[11];
};

__global__ __launch_bounds__(256) void cvt_f32_bf16(CvtArgs a) {
  const int z = blockIdx.y;
  const float4* s = (const float4*)a.src[z];
  u16x4* d = (u16x4*)a.dst[z];
  const int n4 = a.n4[z];
  for (int i = blockIdx.x * blockDim.x + threadIdx.x; i < n4; i += gridDim.x * blockDim.x) {
    float4 v = s[i];
    u16x4 o;
    o[0] = f2bf(v.x); o[1] = f2bf(v.y); o[2] = f2bf(v.z); o[3] = f2bf(v.w);
    d[i] = o;
  }
}

// ---------------- 128x128 4-wave double-buffered GEMM ----------------
// Validated skeleton (R10/R12/R14/R15/R17): per iter vmcnt(0) -> raw s_barrier
// -> stage t+1 -> compute. 64KB LDS -> 2 blocks/CU (m114 overlap, ~800-900 TF).
// Granule-8 both-sides swizzle (0-conflict proven).
template<typename CT>
__global__ __launch_bounds__(256, 2) void gemm_128db(GArgs args) {
  const int z = blockIdx.z;
  const u16* A = (const u16*)args.A[z];
  const u16* W = (const u16*)args.W[z];
  const float* bias = args.bias[z];
  CT* C = (CT*)args.C[z];
  const float oscale = args.oscale[z];
  const int vtrans = args.vtrans[z];

  __shared__ u16 AB[2][2][128 * 64];  // [dbuf][A/B]

  const int tid = threadIdx.x;
  const int lane = tid & 63;
  const int w = tid >> 6;             // 4 waves
  const int wr = w >> 1, wc = w & 1;  // 2x2, 64x64 each
  const int l15 = lane & 15, lhi = lane >> 4;

  // XCD swizzle: grid 8 x 32 per z = 256 blocks; 8 chunks of 32
  const int lin = blockIdx.x + blockIdx.y * 8;
  const int xcd = lin & 7, idx = lin >> 3;
  const int bx = (xcd & 1) * 4 + (idx >> 3);
  const int by = (xcd >> 1) * 8 + (idx & 7);
  const int m0 = by * 128, n0 = bx * 128;

  const int srow = tid >> 3;                               // 0..31
  const int scol = (((tid & 7) ^ ((tid >> 3) & 7)) << 3);  // swizzled source

  f32x4 acc[4][4];
#pragma unroll
  for (int m = 0; m < 4; ++m)
#pragma unroll
    for (int n = 0; n < 4; ++n) acc[m][n] = f32x4{0.f, 0.f, 0.f, 0.f};

  const u16* Abase = A + (size_t)m0 * 1024;
  const u16* Wbase = W + (size_t)n0 * 1024;

  auto stage = [&](int kt, int r) {
    const u16* Ag = Abase + kt * 64;
    const u16* Wg = Wbase + kt * 64;
#pragma unroll
    for (int i = 0; i < 4; ++i) {
      gload_lds16(Ag + (size_t)(i * 32 + srow) * 1024 + scol, &AB[r][0][i * 2048 + w * 512]);
      gload_lds16(Wg + (size_t)(i * 32 + srow) * 1024 + scol, &AB[r][1][i * 2048 + w * 512]);
    }
  };

  stage(0, 0);

  for (int t = 0; t < 16; ++t) {
    const int db = t & 1;

    asm volatile("s_waitcnt vmcnt(0)" ::: "memory");
    __builtin_amdgcn_s_barrier();
    __builtin_amdgcn_sched_barrier(0);

    if (t < 15) stage(t + 1, db ^ 1);

#pragma unroll
    for (int kk = 0; kk < 2; ++kk) {
      short8 af[4], bf[4];
#pragma unroll
      for (int m = 0; m < 4; ++m) {
        int row = wr * 64 + m * 16 + l15;
        af[m] = ldfrag(&AB[db][0][row * 64 + ((kk * 32 + lhi * 8) ^ ((l15 & 7) << 3))]);
      }
#pragma unroll
      for (int n = 0; n < 4; ++n) {
        int row = wc * 64 + n * 16 + l15;
        bf[n] = ldfrag(&AB[db][1][row * 64 + ((kk * 32 + lhi * 8) ^ ((l15 & 7) << 3))]);
      }
      __builtin_amdgcn_s_setprio(1);
#pragma unroll
      for (int m = 0; m < 4; ++m)
#pragma unroll
        for (int n = 0; n < 4; ++n)
          acc[m][n] = __builtin_amdgcn_mfma_f32_16x16x32_bf16(af[m], bf[n], acc[m][n], 0, 0, 0);
      __builtin_amdgcn_s_setprio(0);
    }
  }

#pragma unroll
  for (int m = 0; m < 4; ++m) {
#pragma unroll
    for (int n = 0; n < 4; ++n) {
      int ncol = n0 + wc * 64 + n * 16 + l15;
      float bsv = bias[ncol];
      int mb = m0 + wr * 64 + m * 16 + lhi * 4;
      if (vtrans) {
        int h = ncol >> 6, d = ncol & 63;
        int b = mb >> 10, s0 = sigma_s(mb & 1023);
        u16x4 ov;
#pragma unroll
        for (int r = 0; r < 4; ++r) ov[r] = f2bf((acc[m][n][r] + bsv) * oscale);
        *reinterpret_cast<u16x4*>((u16*)C + ((size_t)((b * 16 + h) * 64 + d)) * 1024 + s0) = ov;
      } else {
#pragma unroll
        for (int r = 0; r < 4; ++r) {
          float val = (acc[m][n][r] + bsv) * oscale;
          if constexpr (sizeof(CT) == 2) ((u16*)C)[(size_t)(mb + r) * 1024 + ncol] = f2bf(val);
          else ((float*)C)[(size_t)(mb + r) * 1024 + ncol] = val;
        }
      }
    }
  }
}

// ---------------- fallback reg-staged GEMM (ws-small path) ----------------
template<typename AT, typename CT>
__global__ __launch_bounds__(256) void gemm_bt_batched(GArgs args) {
  const int z = blockIdx.z;
  const AT* A = (const AT*)args.A[z];
  const float* W = (const float*)args.W[z];
  const float* bias = args.bias[z];
  CT* C = (CT*)args.C[z];
  const float oscale = args.oscale[z];
  const int vtrans = args.vtrans[z];

  __shared__ u16 Al[128][72];
  __shared__ u16 Bl[128][72];

  const int tid = threadIdx.x;
  const int lane = tid & 63;
  const int wid = tid >> 6;
  const int wr = wid >> 1, wc = wid & 1;
  const int m0 = blockIdx.y * 128, n0 = blockIdx.x * 128;
  const int l15 = lane & 15, lhi = lane >> 4;

  const f32x4 vzero = {0.f, 0.f, 0.f, 0.f};
  f32x4 acc[4][4];
#pragma unroll
  for (int i = 0; i < 4; ++i)
#pragma unroll
    for (int j = 0; j < 4; ++j) acc[i][j] = vzero;

  for (int kt = 0; kt < 1024; kt += 64) {
    __syncthreads();
#pragma unroll
    for (int i = 0; i < 8; ++i) {
      int g = tid + i * 256;
      int row = g >> 4, col = (g & 15) * 4;
      u16x4 bv;
      if constexpr (sizeof(AT) == 4) {
        float4 vv = *reinterpret_cast<const float4*>((const float*)A + (size_t)(m0 + row) * 1024 + kt + col);
        bv[0] = f2bf(vv.x); bv[1] = f2bf(vv.y); bv[2] = f2bf(vv.z); bv[3] = f2bf(vv.w);
      } else {
        bv = *reinterpret_cast<const u16x4*>((const u16*)A + (size_t)(m0 + row) * 1024 + kt + col);
      }
      *reinterpret_cast<u16x4*>(&Al[row][col]) = bv;
    }
#pragma unroll
    for (int i = 0; i < 8; ++i) {
      int g = tid + i * 256;
      int row = g >> 4, col = (g & 15) * 4;
      float4 vv = *reinterpret_cast<const float4*>((const float*)W + (size_t)(n0 + row) * 1024 + kt + col);
      u16x4 bv;
      bv[0] = f2bf(vv.x); bv[1] = f2bf(vv.y); bv[2] = f2bf(vv.z); bv[3] = f2bf(vv.w);
      *reinterpret_cast<u16x4*>(&Bl[row][col]) = bv;
    }
    __syncthreads();

#pragma unroll
    for (int c = 0; c < 2; ++c) {
      short8 af[4], bfr[4];
#pragma unroll
      for (int i = 0; i < 4; ++i) af[i] = ldfrag(&Al[wr * 64 + i * 16 + l15][c * 32 + lhi * 8]);
#pragma unroll
      for (int j = 0; j < 4; ++j) bfr[j] = ldfrag(&Bl[wc * 64 + j * 16 + l15][c * 32 + lhi * 8]);
#pragma unroll
      for (int i = 0; i < 4; ++i)
#pragma unroll
        for (int j = 0; j < 4; ++j)
          acc[i][j] = __builtin_amdgcn_mfma_f32_16x16x32_bf16(af[i], bfr[j], acc[i][j], 0, 0, 0);
    }
  }

#pragma unroll
  for (int i = 0; i < 4; ++i) {
#pragma unroll
    for (int j = 0; j < 4; ++j) {
      int n = n0 + wc * 64 + j * 16 + l15;
      float bsv = bias[n];
      int mb = m0 + wr * 64 + i * 16 + lhi * 4;
      if (vtrans) {
        int h = n >> 6, d = n & 63;
        int b = mb >> 10, s0 = sigma_s(mb & 1023);
        u16x4 ov;
#pragma unroll
        for (int r = 0; r < 4; ++r) ov[r] = f2bf((acc[i][j][r] + bsv) * oscale);
        *reinterpret_cast<u16x4*>((u16*)C + ((size_t)((b * 16 + h) * 64 + d)) * 1024 + s0) = ov;
      } else {
#pragma unroll
        for (int r = 0; r < 4; ++r) {
          float val = (acc[i][j][r] + bsv) * oscale;
          if constexpr (sizeof(CT) == 2) ((u16*)C)[(size_t)(mb + r) * 1024 + n] = f2bf(val);
          else ((float*)C)[(size_t)(mb + r) * 1024 + n] = val;
        }
      }
    }
  }
}

// ---------------- flash attention, gload_lds-staged K/V, 64 q/wave ----------------
// R17 softmax (log2-domain, native v_exp_f32). R18 change: K and V staged via
// global_load_lds into linear LDS with the GEMM-proven granule-8 both-sides
// swizzle, using the validated one-barrier skeleton (vmcnt(0) -> s_barrier ->
// stage t+1 -> compute). Removes reg round-trip + second barrier per KV tile.
// V global layout [b][h][d][sigma(s)] is row-major in d -> same staging shape as K.
__global__ __launch_bounds__(256, 2) void attn_fused32e(const u16* q1b, const u16* k1b, const u16* vt1,
                                                        const u16* q2b, const u16* k2b, const u16* vt2,
                                                        u16* o1, u16* o2) {
  const int lin = blockIdx.x + blockIdx.y * 4;       // 0..63
  const int swz = (lin & 7) * 8 + (lin >> 3);
  const int qt = swz & 3;
  const int h = swz >> 2;
  const int zb = blockIdx.z;
  const int path = zb >> 2, b = zb & 3;

  const u16* Q = (path == 0) ? q1b : q2b;
  const u16* K = (path == 0) ? k1b : k2b;
  const u16* V = (path == 0) ? vt1 : vt2;
  u16* O = (path == 0) ? o1 : o2;

  const size_t base_qk = (size_t)b * S_ * D_ + (size_t)h * 64;
  const size_t vbase = (size_t)((b * 16 + h) * 64) * 1024;
  const int tid = threadIdx.x;
  const int lane = tid & 63, w = tid >> 6;
  const int lq = lane & 31, hi = lane >> 5;

  __shared__ u16 Ks[2][64 * 64];
  __shared__ u16 Vs[2][64 * 64];

  const int srow = tid >> 3;                               // 0..31
  const int scol = (((tid & 7) ^ ((tid >> 3) & 7)) << 3);  // swizzled source granule

  const int qbase_row = qt * 256 + w * 64;
  short8 qf[2][4];
#pragma unroll
  for (int qtile = 0; qtile < 2; ++qtile)
#pragma unroll
    for (int dhg = 0; dhg < 4; ++dhg)
      qf[qtile][dhg] = ldfrag(Q + base_qk + (size_t)(qbase_row + qtile * 32 + lq) * 1024 + dhg * 16 + hi * 8);

  f32x16 o_acc[2][2] = {};
  float m_r[2] = {-1e30f, -1e30f};
  float l_r[2] = {0.f, 0.f};
  const float THR = 8.f * 1.44269504f;   // e^8 bound in log2 units

  auto stageKV = [&](int kv, int r) {
    const u16* kg = K + base_qk + (size_t)(kv * 64) * 1024;
    const u16* vg = V + vbase + kv * 64;
#pragma unroll
    for (int i = 0; i < 2; ++i) {
      gload_lds16(kg + (size_t)(i * 32 + srow) * 1024 + scol, &Ks[r][i * 2048 + w * 512]);
      gload_lds16(vg + (size_t)(i * 32 + srow) * 1024 + scol, &Vs[r][i * 2048 + w * 512]);
    }
  };

  stageKV(0, 0);

  for (int kv = 0; kv < 16; ++kv) {
    const int cur = kv & 1;

    asm volatile("s_waitcnt vmcnt(0)" ::: "memory");
    __builtin_amdgcn_s_barrier();
    __builtin_amdgcn_sched_barrier(0);

    if (kv < 15) stageKV(kv + 1, cur ^ 1);

    f32x16 s[2][2] = {};
    __builtin_amdgcn_s_setprio(1);
#pragma unroll
    for (int dhg = 0; dhg < 4; ++dhg) {
#pragma unroll
      for (int keytile = 0; keytile < 2; ++keytile) {
        int row = keytile * 32 + lq;
        short8 ka = ldfrag(&Ks[cur][row * 64 + ((dhg * 16 + hi * 8) ^ ((lq & 7) << 3))]);
#pragma unroll
        for (int qtile = 0; qtile < 2; ++qtile)
          s[keytile][qtile] = __builtin_amdgcn_mfma_f32_32x32x16_bf16(ka, qf[qtile][dhg], s[keytile][qtile], 0, 0, 0);
      }
    }
    __builtin_amdgcn_s_setprio(0);

#pragma unroll
    for (int qtile = 0; qtile < 2; ++qtile) {
      float pm = s[0][qtile][0];
#pragma unroll
      for (int r = 1; r < 16; ++r) pm = fmaxf(pm, s[0][qtile][r]);
#pragma unroll
      for (int r = 0; r < 16; ++r) pm = fmaxf(pm, s[1][qtile][r]);
      pm = fmaxf(pm, __shfl_xor(pm, 32));

      // defer-max: rescale only when log2-max grows beyond THR
      if (!__all(pm <= m_r[qtile] + THR)) {
        float mn = fmaxf(m_r[qtile], pm);
        float sc = fast_exp2(m_r[qtile] - mn);
        m_r[qtile] = mn;
        l_r[qtile] *= sc;
        o_acc[0][qtile] *= sc;
        o_acc[1][qtile] *= sc;
      }
      const float mn = m_r[qtile];
      float sum = 0.f;
#pragma unroll
      for (int kt = 0; kt < 2; ++kt)
#pragma unroll
        for (int r = 0; r < 16; ++r) {
          float e = fast_exp2(s[kt][qtile][r] - mn);
          s[kt][qtile][r] = e;
          sum += e;
        }
      sum += __shfl_xor(sum, 32);
      l_r[qtile] += sum;
    }

    __builtin_amdgcn_s_setprio(1);
#pragma unroll
    for (int g = 0; g < 4; ++g) {
      // rows lq and 32+lq: (32+lq)&7 == lq&7, same XOR
      short8 va0 = ldfrag(&Vs[cur][lq * 64 + ((g * 16 + hi * 8) ^ ((lq & 7) << 3))]);
      short8 va1 = ldfrag(&Vs[cur][(32 + lq) * 64 + ((g * 16 + hi * 8) ^ ((lq & 7) << 3))]);
#pragma unroll
      for (int qtile = 0; qtile < 2; ++qtile) {
        short8 pb;
#pragma unroll
        for (int j = 0; j < 8; ++j) {
          float pv = (g < 2) ? s[0][qtile][(g & 1) * 8 + j] : s[1][qtile][(g & 1) * 8 + j];
          pb[j] = (short)f2bf(pv);
        }
        o_acc[0][qtile] = __builtin_amdgcn_mfma_f32_32x32x16_bf16(va0, pb, o_acc[0][qtile], 0, 0, 0);
        o_acc[1][qtile] = __builtin_amdgcn_mfma_f32_32x32x16_bf16(va1, pb, o_acc[1][qtile], 0, 0, 0);
      }
    }
    __builtin_amdgcn_s_setprio(0);
  }

#pragma unroll
  for (int qtile = 0; qtile < 2; ++qtile) {
    float inv = 1.0f / l_r[qtile];
    u16* Op = O + base_qk + (size_t)(qbase_row + qtile * 32 + lq) * 1024;
#pragma unroll
    for (int dtile = 0; dtile < 2; ++dtile) {
#pragma unroll
      for (int qd = 0; qd < 4; ++qd) {
        u16x4 ov;
#pragma unroll
        for (int r = 0; r < 4; ++r) ov[r] = f2bf(o_acc[dtile][qtile][qd * 4 + r] * inv);
        *reinterpret_cast<u16x4*>(Op + dtile * 32 + 8 * qd + 4 * hi) = ov;
      }
    }
  }
}

extern "C" void kernel_launch(void* const* d_in, const int* in_sizes, int n_in,
                              void* d_out, int out_size, void* d_ws, size_t ws_size,
                              hipStream_t stream) {
  const float* q   = (const float*)d_in[0];
  const float* k   = (const float*)d_in[1];
  const float* v   = (const float*)d_in[2];
  const float* Wq  = (const float*)d_in[3];  const float* bq  = (const float*)d_in[4];
  const float* Wk  = (const float*)d_in[5];  const float* bk  = (const float*)d_in[6];
  const float* Wv  = (const float*)d_in[7];  const float* bv  = (const float*)d_in[8];
  const float* Wq2 = (const float*)d_in[9];  const float* bq2 = (const float*)d_in[10];
  const float* Wk2 = (const float*)d_in[11]; const float* bk2 = (const float*)d_in[12];
  const float* Wv2 = (const float*)d_in[13]; const float* bv2 = (const float*)d_in[14];
  const float* Wc  = (const float*)d_in[15]; const float* bc  = (const float*)d_in[16];
  const float* Wc2 = (const float*)d_in[17]; const float* bc2 = (const float*)d_in[18];

  u16* ws = (u16*)d_ws;
  const size_t SZ = (size_t)M_ * D_;
  const size_t WSZ = (size_t)D_ * D_;
  u16* q1b = ws + 0 * SZ;
  u16* k1b = ws + 1 * SZ;
  u16* vt1 = ws + 2 * SZ;   // [b][h][d][sigma(s)]
  u16* q2b = ws + 3 * SZ;
  u16* k2b = ws + 4 * SZ;
  u16* vt2 = ws + 5 * SZ;
  u16* a1  = ws + 6 * SZ;
  u16* a2  = ws + 7 * SZ;

  const float QSCALE = 0.125f * 1.44269504f;  // 1/sqrt(64) * log2(e)

  const size_t need = (11 * SZ + 8 * WSZ) * sizeof(u16);

  if (ws_size >= need) {
    u16* qb = ws + 8 * SZ;
    u16* kb = ws + 9 * SZ;
    u16* vb = ws + 10 * SZ;
    u16* wbase = ws + 11 * SZ;
    u16* WqB  = wbase + 0 * WSZ;
    u16* WkB  = wbase + 1 * WSZ;
    u16* WvB  = wbase + 2 * WSZ;
    u16* Wq2B = wbase + 3 * WSZ;
    u16* Wk2B = wbase + 4 * WSZ;
    u16* Wv2B = wbase + 5 * WSZ;
    u16* WcB  = wbase + 6 * WSZ;
    u16* Wc2B = wbase + 7 * WSZ;

    CvtArgs ca;
    ca.src[0] = q;   ca.dst[0] = qb;   ca.n4[0] = (int)(SZ / 4);
    ca.src[1] = k;   ca.dst[1] = kb;   ca.n4[1] = (int)(SZ / 4);
    ca.src[2] = v;   ca.dst[2] = vb;   ca.n4[2] = (int)(SZ / 4);
    ca.src[3] = Wq;  ca.dst[3] = WqB;  ca.n4[3] = (int)(WSZ / 4);
    ca.src[4] = Wk;  ca.dst[4] = WkB;  ca.n4[4] = (int)(WSZ / 4);
    ca.src[5] = Wv;  ca.dst[5] = WvB;  ca.n4[5] = (int)(WSZ / 4);
    ca.src[6] = Wq2; ca.dst[6] = Wq2B; ca.n4[6] = (int)(WSZ / 4);
    ca.src[7] = Wk2; ca.dst[7] = Wk2B; ca.n4[7] = (int)(WSZ / 4);
    ca.src[8] = Wv2; ca.dst[8] = Wv2B; ca.n4[8] = (int)(WSZ / 4);
    ca.src[9] = Wc;  ca.dst[9] = WcB;  ca.n4[9] = (int)(WSZ / 4);
    ca.src[10] = Wc2; ca.dst[10] = Wc2B; ca.n4[10] = (int)(WSZ / 4);
    cvt_f32_bf16<<<dim3(512, 11), dim3(256), 0, stream>>>(ca);

    GArgs pa;
    pa.A[0] = qb; pa.W[0] = WqB;  pa.bias[0] = bq;  pa.C[0] = q1b; pa.oscale[0] = QSCALE; pa.vtrans[0] = 0;
    pa.A[1] = kb; pa.W[1] = WkB;  pa.bias[1] = bk;  pa.C[1] = k1b; pa.oscale[1] = 1.0f;   pa.vtrans[1] = 0;
    pa.A[2] = vb; pa.W[2] = WvB;  pa.bias[2] = bv;  pa.C[2] = vt1; pa.oscale[2] = 1.0f;   pa.vtrans[2] = 1;
    pa.A[3] = kb; pa.W[3] = Wq2B; pa.bias[3] = bq2; pa.C[3] = q2b; pa.oscale[3] = QSCALE; pa.vtrans[3] = 0;
    pa.A[4] = qb; pa.W[4] = Wk2B; pa.bias[4] = bk2; pa.C[4] = k2b; pa.oscale[4] = 1.0f;   pa.vtrans[4] = 0;
    pa.A[5] = qb; pa.W[5] = Wv2B; pa.bias[5] = bv2; pa.C[5] = vt2; pa.oscale[5] = 1.0f;   pa.vtrans[5] = 1;
    gemm_128db<u16><<<dim3(8, 32, 6), dim3(256), 0, stream>>>(pa);

    attn_fused32e<<<dim3(4, 16, 8), dim3(256), 0, stream>>>(q1b, k1b, vt1, q2b, k2b, vt2, a1, a2);

    GArgs fa;
    fa.A[0] = a1; fa.W[0] = WcB;  fa.bias[0] = bc;  fa.C[0] = (float*)d_out;      fa.oscale[0] = 1.0f; fa.vtrans[0] = 0;
    fa.A[1] = a2; fa.W[1] = Wc2B; fa.bias[1] = bc2; fa.C[1] = (float*)d_out + SZ; fa.oscale[1] = 1.0f; fa.vtrans[1] = 0;
    gemm_128db<float><<<dim3(8, 32, 2), dim3(256), 0, stream>>>(fa);
  } else {
    GArgs pa;
    pa.A[0] = q; pa.W[0] = Wq;  pa.bias[0] = bq;  pa.C[0] = q1b; pa.oscale[0] = QSCALE; pa.vtrans[0] = 0;
    pa.A[1] = k; pa.W[1] = Wk;  pa.bias[1] = bk;  pa.C[1] = k1b; pa.oscale[1] = 1.0f;   pa.vtrans[1] = 0;
    pa.A[2] = v; pa.W[2] = Wv;  pa.bias[2] = bv;  pa.C[2] = vt1; pa.oscale[2] = 1.0f;   pa.vtrans[2] = 1;
    pa.A[3] = k; pa.W[3] = Wq2; pa.bias[3] = bq2; pa.C[3] = q2b; pa.oscale[3] = QSCALE; pa.vtrans[3] = 0;
    pa.A[4] = q; pa.W[4] = Wk2; pa.bias[4] = bk2; pa.C[4] = k2b; pa.oscale[4] = 1.0f;   pa.vtrans[4] = 0;
    pa.A[5] = q; pa.W[5] = Wv2; pa.bias[5] = bv2; pa.C[5] = vt2; pa.oscale[5] = 1.0f;   pa.vtrans[5] = 1;
    gemm_bt_batched<float, u16><<<dim3(8, 32, 6), dim3(256), 0, stream>>>(pa);

    attn_fused32e<<<dim3(4, 16, 8), dim3(256), 0, stream>>>(q1b, k1b, vt1, q2b, k2b, vt2, a1, a2);

    GArgs fa;
    fa.A[0] = a1; fa.W[0] = Wc;  fa.bias[0] = bc;  fa.C[0] = (float*)d_out;      fa.oscale[0] = 1.0f; fa.vtrans[0] = 0;
    fa.A[1] = a2; fa.W[1] = Wc2; fa.bias[1] = bc2; fa.C[1] = (float*)d_out + SZ; fa.oscale[1] = 1.0f; fa.vtrans[1] = 0;
    gemm_bt_batched<u16, float><<<dim3(8, 32, 2), dim3(256), 0, stream>>>(fa);
  }
}

// Round 19
// 150.078 us; speedup vs baseline: 1.0252x; 1.0252x over previous
//
#include <hip/hip_runtime.h>
#include <hip/hip_bf16.h>

#define B_ 4
#define S_ 1024
#define D_ 1024
#define H_ 16
#define M_ 4096  // B_*S_

typedef unsigned short u16;
typedef __attribute__((ext_vector_type(4))) float f32x4;
typedef __attribute__((ext_vector_type(16))) float f32x16;
typedef __attribute__((ext_vector_type(8))) short short8;
typedef __attribute__((ext_vector_type(4))) u16 u16x4;

__device__ inline u16 f2bf(float f) {
  return __builtin_bit_cast(u16, __float2bfloat16(f));
}

__device__ inline short8 ldfrag(const u16* p) {
  return *reinterpret_cast<const short8*>(p);
}

__device__ inline float fast_exp2(float x) {
  return __builtin_amdgcn_exp2f(x);   // native v_exp_f32 (2^x), no libm path
}

__device__ inline void gload_lds16(const void* g, void* l) {
  __builtin_amdgcn_global_load_lds((const __attribute__((address_space(1))) void*)g,
                                   (__attribute__((address_space(3))) void*)l,
                                   16, 0, 0);
}

// sigma: swap bits 2 and 3 of the sequence index (4-group granular involution)
__device__ inline int sigma_s(int s) {
  return (s & ~12) | ((s & 4) << 1) | ((s & 8) >> 1);
}

struct GArgs {
  const void* A[6];
  const void* W[6];
  const float* bias[6];
  void* C[6];
  float oscale[6];
  int vtrans[6];
};

// ---------------- fp32 -> bf16 bulk convert ----------------
struct CvtArgs {
  const float* src[11];
  u16* dst[11];
  int n4[11];
};

__global__ __launch_bounds__(256) void cvt_f32_bf16(CvtArgs a) {
  const int z = blockIdx.y;
  const float4* s = (const float4*)a.src[z];
  u16x4* d = (u16x4*)a.dst[z];
  const int n4 = a.n4[z];
  for (int i = blockIdx.x * blockDim.x + threadIdx.x; i < n4; i += gridDim.x * blockDim.x) {
    float4 v = s[i];
    u16x4 o;
    o[0] = f2bf(v.x); o[1] = f2bf(v.y); o[2] = f2bf(v.z); o[3] = f2bf(v.w);
    d[i] = o;
  }
}

// ---------------- 128x128 4-wave double-buffered GEMM ----------------
// Validated skeleton (R10/R12/R14/R15/R17): per iter vmcnt(0) -> raw s_barrier
// -> stage t+1 -> compute. 64KB LDS -> 2 blocks/CU (m114 overlap, ~800-900 TF).
// Granule-8 both-sides swizzle (0-conflict proven).
template<typename CT>
__global__ __launch_bounds__(256, 2) void gemm_128db(GArgs args) {
  const int z = blockIdx.z;
  const u16* A = (const u16*)args.A[z];
  const u16* W = (const u16*)args.W[z];
  const float* bias = args.bias[z];
  CT* C = (CT*)args.C[z];
  const float oscale = args.oscale[z];
  const int vtrans = args.vtrans[z];

  __shared__ u16 AB[2][2][128 * 64];  // [dbuf][A/B]

  const int tid = threadIdx.x;
  const int lane = tid & 63;
  const int w = tid >> 6;             // 4 waves
  const int wr = w >> 1, wc = w & 1;  // 2x2, 64x64 each
  const int l15 = lane & 15, lhi = lane >> 4;

  // XCD swizzle: grid 8 x 32 per z = 256 blocks; 8 chunks of 32
  const int lin = blockIdx.x + blockIdx.y * 8;
  const int xcd = lin & 7, idx = lin >> 3;
  const int bx = (xcd & 1) * 4 + (idx >> 3);
  const int by = (xcd >> 1) * 8 + (idx & 7);
  const int m0 = by * 128, n0 = bx * 128;

  const int srow = tid >> 3;                               // 0..31
  const int scol = (((tid & 7) ^ ((tid >> 3) & 7)) << 3);  // swizzled source

  f32x4 acc[4][4];
#pragma unroll
  for (int m = 0; m < 4; ++m)
#pragma unroll
    for (int n = 0; n < 4; ++n) acc[m][n] = f32x4{0.f, 0.f, 0.f, 0.f};

  const u16* Abase = A + (size_t)m0 * 1024;
  const u16* Wbase = W + (size_t)n0 * 1024;

  auto stage = [&](int kt, int r) {
    const u16* Ag = Abase + kt * 64;
    const u16* Wg = Wbase + kt * 64;
#pragma unroll
    for (int i = 0; i < 4; ++i) {
      gload_lds16(Ag + (size_t)(i * 32 + srow) * 1024 + scol, &AB[r][0][i * 2048 + w * 512]);
      gload_lds16(Wg + (size_t)(i * 32 + srow) * 1024 + scol, &AB[r][1][i * 2048 + w * 512]);
    }
  };

  stage(0, 0);

  for (int t = 0; t < 16; ++t) {
    const int db = t & 1;

    asm volatile("s_waitcnt vmcnt(0)" ::: "memory");
    __builtin_amdgcn_s_barrier();
    __builtin_amdgcn_sched_barrier(0);

    if (t < 15) stage(t + 1, db ^ 1);

#pragma unroll
    for (int kk = 0; kk < 2; ++kk) {
      short8 af[4], bf[4];
#pragma unroll
      for (int m = 0; m < 4; ++m) {
        int row = wr * 64 + m * 16 + l15;
        af[m] = ldfrag(&AB[db][0][row * 64 + ((kk * 32 + lhi * 8) ^ ((l15 & 7) << 3))]);
      }
#pragma unroll
      for (int n = 0; n < 4; ++n) {
        int row = wc * 64 + n * 16 + l15;
        bf[n] = ldfrag(&AB[db][1][row * 64 + ((kk * 32 + lhi * 8) ^ ((l15 & 7) << 3))]);
      }
      __builtin_amdgcn_s_setprio(1);
#pragma unroll
      for (int m = 0; m < 4; ++m)
#pragma unroll
        for (int n = 0; n < 4; ++n)
          acc[m][n] = __builtin_amdgcn_mfma_f32_16x16x32_bf16(af[m], bf[n], acc[m][n], 0, 0, 0);
      __builtin_amdgcn_s_setprio(0);
    }
  }

#pragma unroll
  for (int m = 0; m < 4; ++m) {
#pragma unroll
    for (int n = 0; n < 4; ++n) {
      int ncol = n0 + wc * 64 + n * 16 + l15;
      float bsv = bias[ncol];
      int mb = m0 + wr * 64 + m * 16 + lhi * 4;
      if (vtrans) {
        int h = ncol >> 6, d = ncol & 63;
        int b = mb >> 10, s0 = sigma_s(mb & 1023);
        u16x4 ov;
#pragma unroll
        for (int r = 0; r < 4; ++r) ov[r] = f2bf((acc[m][n][r] + bsv) * oscale);
        *reinterpret_cast<u16x4*>((u16*)C + ((size_t)((b * 16 + h) * 64 + d)) * 1024 + s0) = ov;
      } else {
#pragma unroll
        for (int r = 0; r < 4; ++r) {
          float val = (acc[m][n][r] + bsv) * oscale;
          if constexpr (sizeof(CT) == 2) ((u16*)C)[(size_t)(mb + r) * 1024 + ncol] = f2bf(val);
          else ((float*)C)[(size_t)(mb + r) * 1024 + ncol] = val;
        }
      }
    }
  }
}

// ---------------- fallback reg-staged GEMM (ws-small path) ----------------
template<typename AT, typename CT>
__global__ __launch_bounds__(256) void gemm_bt_batched(GArgs args) {
  const int z = blockIdx.z;
  const AT* A = (const AT*)args.A[z];
  const float* W = (const float*)args.W[z];
  const float* bias = args.bias[z];
  CT* C = (CT*)args.C[z];
  const float oscale = args.oscale[z];
  const int vtrans = args.vtrans[z];

  __shared__ u16 Al[128][72];
  __shared__ u16 Bl[128][72];

  const int tid = threadIdx.x;
  const int lane = tid & 63;
  const int wid = tid >> 6;
  const int wr = wid >> 1, wc = wid & 1;
  const int m0 = blockIdx.y * 128, n0 = blockIdx.x * 128;
  const int l15 = lane & 15, lhi = lane >> 4;

  const f32x4 vzero = {0.f, 0.f, 0.f, 0.f};
  f32x4 acc[4][4];
#pragma unroll
  for (int i = 0; i < 4; ++i)
#pragma unroll
    for (int j = 0; j < 4; ++j) acc[i][j] = vzero;

  for (int kt = 0; kt < 1024; kt += 64) {
    __syncthreads();
#pragma unroll
    for (int i = 0; i < 8; ++i) {
      int g = tid + i * 256;
      int row = g >> 4, col = (g & 15) * 4;
      u16x4 bv;
      if constexpr (sizeof(AT) == 4) {
        float4 vv = *reinterpret_cast<const float4*>((const float*)A + (size_t)(m0 + row) * 1024 + kt + col);
        bv[0] = f2bf(vv.x); bv[1] = f2bf(vv.y); bv[2] = f2bf(vv.z); bv[3] = f2bf(vv.w);
      } else {
        bv = *reinterpret_cast<const u16x4*>((const u16*)A + (size_t)(m0 + row) * 1024 + kt + col);
      }
      *reinterpret_cast<u16x4*>(&Al[row][col]) = bv;
    }
#pragma unroll
    for (int i = 0; i < 8; ++i) {
      int g = tid + i * 256;
      int row = g >> 4, col = (g & 15) * 4;
      float4 vv = *reinterpret_cast<const float4*>((const float*)W + (size_t)(n0 + row) * 1024 + kt + col);
      u16x4 bv;
      bv[0] = f2bf(vv.x); bv[1] = f2bf(vv.y); bv[2] = f2bf(vv.z); bv[3] = f2bf(vv.w);
      *reinterpret_cast<u16x4*>(&Bl[row][col]) = bv;
    }
    __syncthreads();

#pragma unroll
    for (int c = 0; c < 2; ++c) {
      short8 af[4], bfr[4];
#pragma unroll
      for (int i = 0; i < 4; ++i) af[i] = ldfrag(&Al[wr * 64 + i * 16 + l15][c * 32 + lhi * 8]);
#pragma unroll
      for (int j = 0; j < 4; ++j) bfr[j] = ldfrag(&Bl[wc * 64 + j * 16 + l15][c * 32 + lhi * 8]);
#pragma unroll
      for (int i = 0; i < 4; ++i)
#pragma unroll
        for (int j = 0; j < 4; ++j)
          acc[i][j] = __builtin_amdgcn_mfma_f32_16x16x32_bf16(af[i], bfr[j], acc[i][j], 0, 0, 0);
    }
  }

#pragma unroll
  for (int i = 0; i < 4; ++i) {
#pragma unroll
    for (int j = 0; j < 4; ++j) {
      int n = n0 + wc * 64 + j * 16 + l15;
      float bsv = bias[n];
      int mb = m0 + wr * 64 + i * 16 + lhi * 4;
      if (vtrans) {
        int h = n >> 6, d = n & 63;
        int b = mb >> 10, s0 = sigma_s(mb & 1023);
        u16x4 ov;
#pragma unroll
        for (int r = 0; r < 4; ++r) ov[r] = f2bf((acc[i][j][r] + bsv) * oscale);
        *reinterpret_cast<u16x4*>((u16*)C + ((size_t)((b * 16 + h) * 64 + d)) * 1024 + s0) = ov;
      } else {
#pragma unroll
        for (int r = 0; r < 4; ++r) {
          float val = (acc[i][j][r] + bsv) * oscale;
          if constexpr (sizeof(CT) == 2) ((u16*)C)[(size_t)(mb + r) * 1024 + n] = f2bf(val);
          else ((float*)C)[(size_t)(mb + r) * 1024 + n] = val;
        }
      }
    }
  }
}

// ---------------- LDS-staged 32x32 flash attention, 64 q/wave (R17-exact) ----------------
// Log2-domain softmax (Q pre-scaled by 0.125*log2e); exp via native
// v_exp_f32 builtin (__builtin_amdgcn_exp2f) -- NOT libm exp2f (R16 lesson:
// libm exp2f is a ~30-inst slow path, +28 VGPR, 3x attn dur).
__global__ __launch_bounds__(256, 2) void attn_fused32b(const u16* q1b, const u16* k1b, const u16* vt1,
                                                        const u16* q2b, const u16* k2b, const u16* vt2,
                                                        u16* o1, u16* o2) {
  const int lin = blockIdx.x + blockIdx.y * 4;       // 0..63
  const int swz = (lin & 7) * 8 + (lin >> 3);
  const int qt = swz & 3;
  const int h = swz >> 2;
  const int zb = blockIdx.z;
  const int path = zb >> 2, b = zb & 3;

  const u16* Q = (path == 0) ? q1b : q2b;
  const u16* K = (path == 0) ? k1b : k2b;
  const u16* V = (path == 0) ? vt1 : vt2;
  u16* O = (path == 0) ? o1 : o2;

  const size_t base_qk = (size_t)b * S_ * D_ + (size_t)h * 64;
  const size_t vbase = (size_t)((b * 16 + h) * 64) * 1024;
  const int tid = threadIdx.x;
  const int lane = tid & 63, w = tid >> 6;
  const int lq = lane & 31, hi = lane >> 5;

  __shared__ u16 Ks[2][64][72];
  __shared__ u16 Vs[2][64][72];

  const int srow = tid >> 3;
  const int scol = (tid & 7) * 8;

  const int qbase_row = qt * 256 + w * 64;
  short8 qf[2][4];
#pragma unroll
  for (int qtile = 0; qtile < 2; ++qtile)
#pragma unroll
    for (int dhg = 0; dhg < 4; ++dhg)
      qf[qtile][dhg] = ldfrag(Q + base_qk + (size_t)(qbase_row + qtile * 32 + lq) * 1024 + dhg * 16 + hi * 8);

  f32x16 o_acc[2][2] = {};
  float m_r[2] = {-1e30f, -1e30f};
  float l_r[2] = {0.f, 0.f};
  const float THR = 8.f * 1.44269504f;   // e^8 bound in log2 units

  {
    short8 r0 = ldfrag(K + base_qk + (size_t)srow * 1024 + scol);
    short8 r1 = ldfrag(K + base_qk + (size_t)(srow + 32) * 1024 + scol);
    short8 r2 = ldfrag(V + vbase + (size_t)srow * 1024 + scol);
    short8 r3 = ldfrag(V + vbase + (size_t)(srow + 32) * 1024 + scol);
    *reinterpret_cast<short8*>(&Ks[0][srow][scol]) = r0;
    *reinterpret_cast<short8*>(&Ks[0][srow + 32][scol]) = r1;
    *reinterpret_cast<short8*>(&Vs[0][srow][scol]) = r2;
    *reinterpret_cast<short8*>(&Vs[0][srow + 32][scol]) = r3;
  }
  __syncthreads();

  for (int kv = 0; kv < 16; ++kv) {
    const int cur = kv & 1;

    short8 n0, n1, n2, n3;
    if (kv < 15) {
      const u16* kg = K + base_qk + (size_t)((kv + 1) * 64) * 1024;
      const u16* vg = V + vbase + (kv + 1) * 64;
      n0 = ldfrag(kg + (size_t)srow * 1024 + scol);
      n1 = ldfrag(kg + (size_t)(srow + 32) * 1024 + scol);
      n2 = ldfrag(vg + (size_t)srow * 1024 + scol);
      n3 = ldfrag(vg + (size_t)(srow + 32) * 1024 + scol);
    }

    f32x16 s[2][2] = {};
    __builtin_amdgcn_s_setprio(1);
#pragma unroll
    for (int dhg = 0; dhg < 4; ++dhg) {
#pragma unroll
      for (int keytile = 0; keytile < 2; ++keytile) {
        short8 ka = ldfrag(&Ks[cur][keytile * 32 + lq][dhg * 16 + hi * 8]);
#pragma unroll
        for (int qtile = 0; qtile < 2; ++qtile)
          s[keytile][qtile] = __builtin_amdgcn_mfma_f32_32x32x16_bf16(ka, qf[qtile][dhg], s[keytile][qtile], 0, 0, 0);
      }
    }
    __builtin_amdgcn_s_setprio(0);

#pragma unroll
    for (int qtile = 0; qtile < 2; ++qtile) {
      float pm = s[0][qtile][0];
#pragma unroll
      for (int r = 1; r < 16; ++r) pm = fmaxf(pm, s[0][qtile][r]);
#pragma unroll
      for (int r = 0; r < 16; ++r) pm = fmaxf(pm, s[1][qtile][r]);
      pm = fmaxf(pm, __shfl_xor(pm, 32));

      // defer-max: rescale only when log2-max grows beyond THR
      if (!__all(pm <= m_r[qtile] + THR)) {
        float mn = fmaxf(m_r[qtile], pm);
        float sc = fast_exp2(m_r[qtile] - mn);
        m_r[qtile] = mn;
        l_r[qtile] *= sc;
        o_acc[0][qtile] *= sc;
        o_acc[1][qtile] *= sc;
      }
      const float mn = m_r[qtile];
      float sum = 0.f;
#pragma unroll
      for (int kt = 0; kt < 2; ++kt)
#pragma unroll
        for (int r = 0; r < 16; ++r) {
          float e = fast_exp2(s[kt][qtile][r] - mn);
          s[kt][qtile][r] = e;
          sum += e;
        }
      sum += __shfl_xor(sum, 32);
      l_r[qtile] += sum;
    }

    __builtin_amdgcn_s_setprio(1);
#pragma unroll
    for (int g = 0; g < 4; ++g) {
      short8 va0 = ldfrag(&Vs[cur][lq][g * 16 + hi * 8]);
      short8 va1 = ldfrag(&Vs[cur][32 + lq][g * 16 + hi * 8]);
#pragma unroll
      for (int qtile = 0; qtile < 2; ++qtile) {
        short8 pb;
#pragma unroll
        for (int j = 0; j < 8; ++j) {
          float pv = (g < 2) ? s[0][qtile][(g & 1) * 8 + j] : s[1][qtile][(g & 1) * 8 + j];
          pb[j] = (short)f2bf(pv);
        }
        o_acc[0][qtile] = __builtin_amdgcn_mfma_f32_32x32x16_bf16(va0, pb, o_acc[0][qtile], 0, 0, 0);
        o_acc[1][qtile] = __builtin_amdgcn_mfma_f32_32x32x16_bf16(va1, pb, o_acc[1][qtile], 0, 0, 0);
      }
    }
    __builtin_amdgcn_s_setprio(0);

    __syncthreads();
    if (kv < 15) {
      const int nxt = cur ^ 1;
      *reinterpret_cast<short8*>(&Ks[nxt][srow][scol]) = n0;
      *reinterpret_cast<short8*>(&Ks[nxt][srow + 32][scol]) = n1;
      *reinterpret_cast<short8*>(&Vs[nxt][srow][scol]) = n2;
      *reinterpret_cast<short8*>(&Vs[nxt][srow + 32][scol]) = n3;
      __syncthreads();
    }
  }

#pragma unroll
  for (int qtile = 0; qtile < 2; ++qtile) {
    float inv = 1.0f / l_r[qtile];
    u16* Op = O + base_qk + (size_t)(qbase_row + qtile * 32 + lq) * 1024;
#pragma unroll
    for (int dtile = 0; dtile < 2; ++dtile) {
#pragma unroll
      for (int qd = 0; qd < 4; ++qd) {
        u16x4 ov;
#pragma unroll
        for (int r = 0; r < 4; ++r) ov[r] = f2bf(o_acc[dtile][qtile][qd * 4 + r] * inv);
        *reinterpret_cast<u16x4*>(Op + dtile * 32 + 8 * qd + 4 * hi) = ov;
      }
    }
  }
}

extern "C" void kernel_launch(void* const* d_in, const int* in_sizes, int n_in,
                              void* d_out, int out_size, void* d_ws, size_t ws_size,
                              hipStream_t stream) {
  const float* q   = (const float*)d_in[0];
  const float* k   = (const float*)d_in[1];
  const float* v   = (const float*)d_in[2];
  const float* Wq  = (const float*)d_in[3];  const float* bq  = (const float*)d_in[4];
  const float* Wk  = (const float*)d_in[5];  const float* bk  = (const float*)d_in[6];
  const float* Wv  = (const float*)d_in[7];  const float* bv  = (const float*)d_in[8];
  const float* Wq2 = (const float*)d_in[9];  const float* bq2 = (const float*)d_in[10];
  const float* Wk2 = (const float*)d_in[11]; const float* bk2 = (const float*)d_in[12];
  const float* Wv2 = (const float*)d_in[13]; const float* bv2 = (const float*)d_in[14];
  const float* Wc  = (const float*)d_in[15]; const float* bc  = (const float*)d_in[16];
  const float* Wc2 = (const float*)d_in[17]; const float* bc2 = (const float*)d_in[18];

  u16* ws = (u16*)d_ws;
  const size_t SZ = (size_t)M_ * D_;
  const size_t WSZ = (size_t)D_ * D_;
  u16* q1b = ws + 0 * SZ;
  u16* k1b = ws + 1 * SZ;
  u16* vt1 = ws + 2 * SZ;   // [b][h][d][sigma(s)]
  u16* q2b = ws + 3 * SZ;
  u16* k2b = ws + 4 * SZ;
  u16* vt2 = ws + 5 * SZ;
  u16* a1  = ws + 6 * SZ;
  u16* a2  = ws + 7 * SZ;

  const float QSCALE = 0.125f * 1.44269504f;  // 1/sqrt(64) * log2(e)

  const size_t need = (11 * SZ + 8 * WSZ) * sizeof(u16);

  if (ws_size >= need) {
    u16* qb = ws + 8 * SZ;
    u16* kb = ws + 9 * SZ;
    u16* vb = ws + 10 * SZ;
    u16* wbase = ws + 11 * SZ;
    u16* WqB  = wbase + 0 * WSZ;
    u16* WkB  = wbase + 1 * WSZ;
    u16* WvB  = wbase + 2 * WSZ;
    u16* Wq2B = wbase + 3 * WSZ;
    u16* Wk2B = wbase + 4 * WSZ;
    u16* Wv2B = wbase + 5 * WSZ;
    u16* WcB  = wbase + 6 * WSZ;
    u16* Wc2B = wbase + 7 * WSZ;

    CvtArgs ca;
    ca.src[0] = q;   ca.dst[0] = qb;   ca.n4[0] = (int)(SZ / 4);
    ca.src[1] = k;   ca.dst[1] = kb;   ca.n4[1] = (int)(SZ / 4);
    ca.src[2] = v;   ca.dst[2] = vb;   ca.n4[2] = (int)(SZ / 4);
    ca.src[3] = Wq;  ca.dst[3] = WqB;  ca.n4[3] = (int)(WSZ / 4);
    ca.src[4] = Wk;  ca.dst[4] = WkB;  ca.n4[4] = (int)(WSZ / 4);
    ca.src[5] = Wv;  ca.dst[5] = WvB;  ca.n4[5] = (int)(WSZ / 4);
    ca.src[6] = Wq2; ca.dst[6] = Wq2B; ca.n4[6] = (int)(WSZ / 4);
    ca.src[7] = Wk2; ca.dst[7] = Wk2B; ca.n4[7] = (int)(WSZ / 4);
    ca.src[8] = Wv2; ca.dst[8] = Wv2B; ca.n4[8] = (int)(WSZ / 4);
    ca.src[9] = Wc;  ca.dst[9] = WcB;  ca.n4[9] = (int)(WSZ / 4);
    ca.src[10] = Wc2; ca.dst[10] = Wc2B; ca.n4[10] = (int)(WSZ / 4);
    cvt_f32_bf16<<<dim3(512, 11), dim3(256), 0, stream>>>(ca);

    GArgs pa;
    pa.A[0] = qb; pa.W[0] = WqB;  pa.bias[0] = bq;  pa.C[0] = q1b; pa.oscale[0] = QSCALE; pa.vtrans[0] = 0;
    pa.A[1] = kb; pa.W[1] = WkB;  pa.bias[1] = bk;  pa.C[1] = k1b; pa.oscale[1] = 1.0f;   pa.vtrans[1] = 0;
    pa.A[2] = vb; pa.W[2] = WvB;  pa.bias[2] = bv;  pa.C[2] = vt1; pa.oscale[2] = 1.0f;   pa.vtrans[2] = 1;
    pa.A[3] = kb; pa.W[3] = Wq2B; pa.bias[3] = bq2; pa.C[3] = q2b; pa.oscale[3] = QSCALE; pa.vtrans[3] = 0;
    pa.A[4] = qb; pa.W[4] = Wk2B; pa.bias[4] = bk2; pa.C[4] = k2b; pa.oscale[4] = 1.0f;   pa.vtrans[4] = 0;
    pa.A[5] = qb; pa.W[5] = Wv2B; pa.bias[5] = bv2; pa.C[5] = vt2; pa.oscale[5] = 1.0f;   pa.vtrans[5] = 1;
    gemm_128db<u16><<<dim3(8, 32, 6), dim3(256), 0, stream>>>(pa);

    attn_fused32b<<<dim3(4, 16, 8), dim3(256), 0, stream>>>(q1b, k1b, vt1, q2b, k2b, vt2, a1, a2);

    GArgs fa;
    fa.A[0] = a1; fa.W[0] = WcB;  fa.bias[0] = bc;  fa.C[0] = (float*)d_out;      fa.oscale[0] = 1.0f; fa.vtrans[0] = 0;
    fa.A[1] = a2; fa.W[1] = Wc2B; fa.bias[1] = bc2; fa.C[1] = (float*)d_out + SZ; fa.oscale[1] = 1.0f; fa.vtrans[1] = 0;
    gemm_128db<float><<<dim3(8, 32, 2), dim3(256), 0, stream>>>(fa);
  } else {
    GArgs pa;
    pa.A[0] = q; pa.W[0] = Wq;  pa.bias[0] = bq;  pa.C[0] = q1b; pa.oscale[0] = QSCALE; pa.vtrans[0] = 0;
    pa.A[1] = k; pa.W[1] = Wk;  pa.bias[1] = bk;  pa.C[1] = k1b; pa.oscale[1] = 1.0f;   pa.vtrans[1] = 0;
    pa.A[2] = v; pa.W[2] = Wv;  pa.bias[2] = bv;  pa.C[2] = vt1; pa.oscale[2] = 1.0f;   pa.vtrans[2] = 1;
    pa.A[3] = k; pa.W[3] = Wq2; pa.bias[3] = bq2; pa.C[3] = q2b; pa.oscale[3] = QSCALE; pa.vtrans[3] = 0;
    pa.A[4] = q; pa.W[4] = Wk2; pa.bias[4] = bk2; pa.C[4] = k2b; pa.oscale[4] = 1.0f;   pa.vtrans[4] = 0;
    pa.A[5] = q; pa.W[5] = Wv2; pa.bias[5] = bv2; pa.C[5] = vt2; pa.oscale[5] = 1.0f;   pa.vtrans[5] = 1;
    gemm_bt_batched<float, u16><<<dim3(8, 32, 6), dim3(256), 0, stream>>>(pa);

    attn_fused32b<<<dim3(4, 16, 8), dim3(256), 0, stream>>>(q1b, k1b, vt1, q2b, k2b, vt2, a1, a2);

    GArgs fa;
    fa.A[0] = a1; fa.W[0] = Wc;  fa.bias[0] = bc;  fa.C[0] = (float*)d_out;      fa.oscale[0] = 1.0f; fa.vtrans[0] = 0;
    fa.A[1] = a2; fa.W[1] = Wc2; fa.bias[1] = bc2; fa.C[1] = (float*)d_out + SZ; fa.oscale[1] = 1.0f; fa.vtrans[1] = 0;
    gemm_bt_batched<u16, float><<<dim3(8, 32, 2), dim3(256), 0, stream>>>(fa);
  }
}